// Round 1
// baseline (285.007 us; speedup 1.0000x reference)
//
#include <hip/hip_runtime.h>

// SQDDPG mixer, MI355X. Round 6: prefix-major row remap -> triangular
// layer-1 (MFMA 128->80/wave, A-frag builds 32->8/pass); drop nh un-halving
// (acc[4][4] under (256,3) = 170-reg cap; R4's spill was the (256,4) 128
// cap); h1 XOR lane-swizzle (involution, both sides) -> conflict-free
// scatter; pack merged into prep (one fewer launch).
//
// Frozen validated facts (R2/R3): threefry partitionable, bits=o0^o1,
// counter (0, b*128+n); stable ranks; coalition slot j <- qs[inv_l[j]];
// output agent n reads prefix-row pos_l[n]; B-frag pack order: slot
// (t,u,L) elem j -> B[k=t*32+(L>>4)*8+j][n=u*16+(L&15)].
// NEW row map (this round): M-row = prefix*8 + (s&7), pass p = s>>3.
//   tile mt holds prefixes {2mt,2mt+1}; K-slice t contributes iff t<=mt;
//   diagonal mask on = (q>>1) <= (l15>>3), t- and mt-independent.
// h1 swizzle: logical (frag,lane',j) stored at unit frag*64 + (lane' ^
//   ((lane'>>3)&3)), elem j. Reader uses Lsw = L ^ ((L>>3)&3).

#define A_N   8
#define NA_N  16
#define S_N   16
#define SD    256
#define EMB   256
#define B_TOT 1024

typedef __bf16 bf16x8 __attribute__((ext_vector_type(8)));
typedef float  f32x4  __attribute__((ext_vector_type(4)));

__device__ __forceinline__ f32x4 splat4(float v) {
  f32x4 x; x[0] = v; x[1] = v; x[2] = v; x[3] = v; return x;
}
__device__ __forceinline__ bf16x8 zero8() {
  bf16x8 z;
#pragma unroll
  for (int j = 0; j < 8; ++j) z[j] = (__bf16)0.0f;
  return z;
}

// ---------------------------------------------------------------------------
// JAX threefry2x32, key = (0, 42); partitionable draw: bits = o0 ^ o1.
// ---------------------------------------------------------------------------
__device__ __forceinline__ float jax_uniform(unsigned idx) {
  const unsigned ks0 = 0u, ks1 = 42u, ks2 = 0x1BD11BDAu ^ 42u;
  unsigned x0 = 0u + ks0;
  unsigned x1 = idx + ks1;
#define TF_RND(r) { x0 += x1; x1 = (x1 << (r)) | (x1 >> (32 - (r))); x1 ^= x0; }
  TF_RND(13) TF_RND(15) TF_RND(26) TF_RND(6)  x0 += ks1; x1 += ks2 + 1u;
  TF_RND(17) TF_RND(29) TF_RND(16) TF_RND(24) x0 += ks2; x1 += ks0 + 2u;
  TF_RND(13) TF_RND(15) TF_RND(26) TF_RND(6)  x0 += ks0; x1 += ks1 + 3u;
  TF_RND(17) TF_RND(29) TF_RND(16) TF_RND(24) x0 += ks1; x1 += ks2 + 4u;
  TF_RND(13) TF_RND(15) TF_RND(26) TF_RND(6)  x0 += ks2; x1 += ks0 + 5u;
#undef TF_RND
  const unsigned bits = x0 ^ x1;
  return __uint_as_float((bits >> 9) | 0x3F800000u) - 1.0f;
}

// ---------------------------------------------------------------------------
// Merged prep (blocks 0..511: sW + V-net, 2 b each) + pack (blocks 512..559:
// bf16 B-frag repack of W1-bottom and W2). One launch instead of two; pack's
// 48 latency-bound blocks hide under prep's streaming.
// ---------------------------------------------------------------------------
__global__ __launch_bounds__(256) void prep_pack_kernel(
    const float* __restrict__ states, const float* __restrict__ W1,
    const float* __restrict__ b1, const float* __restrict__ Vw1,
    const float* __restrict__ Vb1, const float* __restrict__ Vw2,
    const float* __restrict__ Vb2, const float* __restrict__ W2,
    float* __restrict__ sW, float* __restrict__ vout,
    __bf16* __restrict__ W1b_bf, __bf16* __restrict__ W2_bf) {
  __shared__ float st_l[2][SD];
  __shared__ float red_l[2][4];

  if (blockIdx.x >= 512) {  // ---- pack path ----
    const int ts = (blockIdx.x - 512) * 256 + threadIdx.x;  // 0..12287
    if (ts < 4096) {                                // W1 bottom: t=0..3
      const int t = ts >> 10, rem = ts & 1023, u = rem >> 6, Lp = rem & 63;
      const int qp = Lp >> 4, l15p = Lp & 15;
#pragma unroll
      for (int j = 0; j < 8; ++j) {
        const int k = t * 32 + qp * 8 + j, nn = u * 16 + l15p;
        W1b_bf[ts * 8 + j] = (__bf16)W1[(SD + k) * EMB + nn];
      }
    } else {                                        // W2: t=0..7
      const int ts2 = ts - 4096;
      const int t = ts2 >> 10, rem = ts2 & 1023, u = rem >> 6, Lp = rem & 63;
      const int qp = Lp >> 4, l15p = Lp & 15;
#pragma unroll
      for (int j = 0; j < 8; ++j) {
        const int k = t * 32 + qp * 8 + j, nn = u * 16 + l15p;
        W2_bf[ts2 * 8 + j] = (__bf16)W2[k * EMB + nn];
      }
    }
    return;
  }

  // ---- prep path ----
  const int b0 = blockIdx.x * 2;
  const int n = threadIdx.x;

#pragma unroll
  for (int i = 0; i < 2; ++i) st_l[i][n] = states[(b0 + i) * SD + n];
  __syncthreads();

  float aS[2], aV[2];
  const float b1n = b1[n], vb1n = Vb1[n];
#pragma unroll
  for (int i = 0; i < 2; ++i) { aS[i] = b1n; aV[i] = vb1n; }

#pragma unroll 8
  for (int k = 0; k < SD; ++k) {
    const float wv = W1[k * EMB + n];
    const float vw = Vw1[k * EMB + n];
#pragma unroll
    for (int i = 0; i < 2; ++i) {
      const float s = st_l[i][k];
      aS[i] = fmaf(s, wv, aS[i]);
      aV[i] = fmaf(s, vw, aV[i]);
    }
  }
#pragma unroll
  for (int i = 0; i < 2; ++i) sW[(b0 + i) * EMB + n] = aS[i];

  const float vw2 = Vw2[n];
#pragma unroll
  for (int i = 0; i < 2; ++i) {
    float c = fmaxf(aV[i], 0.f) * vw2;
#pragma unroll
    for (int off = 32; off; off >>= 1) c += __shfl_down(c, off);
    if ((n & 63) == 0) red_l[i][n >> 6] = c;
  }
  __syncthreads();
  if (n < 2)
    vout[b0 + n] = red_l[n][0] + red_l[n][1] + red_l[n][2] + red_l[n][3] + Vb2[0];
}

// ---------------------------------------------------------------------------
// Main: 1024 blocks (one per b), 256 threads = 4 waves. Two passes of M=64,
// prefix-major rows, triangular layer-1, single full-N sweep (acc[4][4]).
// ---------------------------------------------------------------------------
__global__ __launch_bounds__(256, 3) void main_kernel(
    const float* __restrict__ agent_qs, const float* __restrict__ b2g,
    const float* __restrict__ W3, const float* __restrict__ b3,
    const float* __restrict__ sW, const float* __restrict__ vv,
    const __bf16* __restrict__ W1b_bf, const __bf16* __restrict__ W2_bf,
    float* __restrict__ out) {
  __shared__ bf16x8 h1_l[32 * 64];      // 32 KB: layer2 A-frags (swizzled)
  __shared__ __attribute__((aligned(16))) __bf16 qs_bf[A_N * NA_N];
  __shared__ float u_l[128];
  __shared__ int   inv_l[128];          // inv_l[s*8+a] = rank of agent a
  __shared__ int   pos_l[128];          // pos_l[s*8+r] = agent with rank r
  __shared__ float adv_part[4][64];
  __shared__ float marg_l[128];         // marg_l[p*64 + prefix*8 + (s&7)]

  const int b = blockIdx.x;
  const int n = threadIdx.x;
  const int w = n >> 6, L = n & 63, q = L >> 4, l15 = L & 15;
  const int s7 = l15 & 7;        // s low bits (A-frag / C-row role)
  const int sl = l15 >> 3;       // prefix low bit (A-frag side)
  const int jq = q >> 1;         // jcoal low bit
  const int na0 = (q & 1) * 8;   // action sub-block
  const int Lsw = L ^ ((L >> 3) & 3);  // swizzled layer-2 read lane

  if (n < 128) {
    qs_bf[n] = (__bf16)agent_qs[b * 128 + n];
    u_l[n] = jax_uniform((unsigned)(b * 128 + n));
  }
  __syncthreads();

  if (n < 128) {
    const int s = n >> 3, a = n & 7;
    const float u = u_l[n];
    int r = 0;
#pragma unroll
    for (int a2 = 0; a2 < A_N; ++a2) {
      const float u2 = u_l[s * 8 + a2];
      r += (u2 < u || (u2 == u && a2 < a)) ? 1 : 0;
    }
    inv_l[n] = r;
    pos_l[s * 8 + r] = a;
  }
  __syncthreads();

  // diagonal-tile mask: t==mt -> on iff jcoal<=prefix iff jq<=sl
  const bool diag_on = (jq <= sl);

  // p-invariant global loads, hoisted
  float svv[4], bvv[4], w3v[4];
#pragma unroll
  for (int c = 0; c < 4; ++c) {
    const int col = (w * 4 + c) * 16 + l15;
    svv[c] = sW[b * EMB + col];
    bvv[c] = b2g[col];
    w3v[c] = W3[col];
  }

#pragma unroll 1
  for (int p = 0; p < 2; ++p) {
    // ---- layer 1: triangular (64x128)@W1b(128x256), C init sW[col] ----
    f32x4 acc[4][4];
#pragma unroll
    for (int c = 0; c < 4; ++c)
#pragma unroll
      for (int mt = 0; mt < 4; ++mt) acc[mt][c] = splat4(svv[c]);

    const int invbase = (p * 8 + s7) * 8;
#pragma unroll
    for (int t = 0; t < 4; ++t) {
      const int ag = inv_l[invbase + 2 * t + jq];
      const bf16x8 afb = *(const bf16x8*)&qs_bf[ag * NA_N + na0];
      const bf16x8 afd = diag_on ? afb : zero8();
#pragma unroll
      for (int c = 0; c < 4; ++c) {
        const bf16x8 bfr = *(const bf16x8*)
            &W1b_bf[((t * 16 + w * 4 + c) * 64 + L) * 8];
#pragma unroll
        for (int mt = 0; mt < 4; ++mt) {
          if (mt < t) continue;  // compile-time folded: t>mt is exact zero
          acc[mt][c] = __builtin_amdgcn_mfma_f32_16x16x32_bf16(
              (mt == t) ? afd : afb, bfr, acc[mt][c], 0, 0, 0);
        }
      }
    }

    // relu -> bf16 swizzled scatter (conflict-free: bank enum verified)
    {
      __bf16* h1e = (__bf16*)h1_l;
#pragma unroll
      for (int c = 0; c < 4; ++c) {
        const int X = w * 4 + c;
        const int hi = (X & 1) * 2 + sl;
        const int xr = (q >> 1) | ((hi & 1) << 1);
#pragma unroll
        for (int mt = 0; mt < 4; ++mt) {
          const int ub = ((X >> 1) * 4 + mt) * 64 + (hi << 4);
#pragma unroll
          for (int r = 0; r < 4; ++r) {
            const float v = fmaxf(acc[mt][c][r], 0.f);
            const int u = ub + ((q * 4 + r) ^ xr);
            h1e[u * 8 + s7] = (__bf16)v;
          }
        }
      }
    }
    __syncthreads();

    // ---- layer 2: (64x256)@W2(256x256), A-frags read once per (t,mt) ----
    f32x4 acc2[4][4];
#pragma unroll
    for (int c = 0; c < 4; ++c)
#pragma unroll
      for (int mt = 0; mt < 4; ++mt) acc2[mt][c] = splat4(bvv[c]);

#pragma unroll
    for (int t = 0; t < 8; ++t) {
      bf16x8 af[4];
#pragma unroll
      for (int mt = 0; mt < 4; ++mt) af[mt] = h1_l[(t * 4 + mt) * 64 + Lsw];
#pragma unroll
      for (int c = 0; c < 4; ++c) {
        const bf16x8 bfr = *(const bf16x8*)
            &W2_bf[((t * 16 + w * 4 + c) * 64 + L) * 8];
#pragma unroll
        for (int mt = 0; mt < 4; ++mt)
          acc2[mt][c] = __builtin_amdgcn_mfma_f32_16x16x32_bf16(
              af[mt], bfr, acc2[mt][c], 0, 0, 0);
      }
    }

    // ---- layer 3 partials + 16-lane reduce ----
    float psum[4][4];
#pragma unroll
    for (int mt = 0; mt < 4; ++mt)
#pragma unroll
      for (int r = 0; r < 4; ++r) psum[mt][r] = 0.f;
#pragma unroll
    for (int c = 0; c < 4; ++c)
#pragma unroll
      for (int mt = 0; mt < 4; ++mt)
#pragma unroll
        for (int r = 0; r < 4; ++r)
          psum[mt][r] = fmaf(fmaxf(acc2[mt][c][r], 0.f), w3v[c], psum[mt][r]);

#pragma unroll
    for (int mt = 0; mt < 4; ++mt) {
#pragma unroll
      for (int r = 0; r < 4; ++r) {
        float sum = psum[mt][r];
#pragma unroll
        for (int off = 1; off < 16; off <<= 1) sum += __shfl_xor(sum, off);
        if (l15 == 0) adv_part[w][mt * 16 + q * 4 + r] = sum;
      }
    }
    __syncthreads();
    if (n < 64)
      marg_l[p * 64 + n] = adv_part[0][n] + adv_part[1][n] +
                           adv_part[2][n] + adv_part[3][n];
    __syncthreads();
  }

  // ---- gather: agent a at sample s -> row prefix*8 + (s&7), p = s>>3 ----
  if (n < A_N) {
    float sh = 0.f;
#pragma unroll
    for (int s = 0; s < S_N; ++s) {
      const int pr = pos_l[s * 8 + n];
      sh += marg_l[((s >> 3) << 6) + pr * 8 + (s & 7)];
    }
    out[b * A_N + n] = sh * (1.f / 16.f) + b3[0] + vv[b];
  }
}

// ---------------------------------------------------------------------------
extern "C" void kernel_launch(void* const* d_in, const int* in_sizes, int n_in,
                              void* d_out, int out_size, void* d_ws,
                              size_t ws_size, hipStream_t stream) {
  const float* states   = (const float*)d_in[0];
  const float* agent_qs = (const float*)d_in[1];
  const float* W1       = (const float*)d_in[2];
  const float* b1       = (const float*)d_in[3];
  const float* W2       = (const float*)d_in[4];
  const float* b2       = (const float*)d_in[5];
  const float* W3       = (const float*)d_in[6];
  const float* b3       = (const float*)d_in[7];
  const float* Vw1      = (const float*)d_in[8];
  const float* Vb1      = (const float*)d_in[9];
  const float* Vw2      = (const float*)d_in[10];
  const float* Vb2      = (const float*)d_in[11];
  float* out = (float*)d_out;

  char* ws = (char*)d_ws;
  float*  sW     = (float*)(ws);                     // 1 MB
  float*  vv     = (float*)(ws + 1048576);           // 4 KB
  __bf16* W1b_bf = (__bf16*)(ws + 1052672);          // 64 KB
  __bf16* W2_bf  = (__bf16*)(ws + 1118208);          // 128 KB

  prep_pack_kernel<<<560, 256, 0, stream>>>(states, W1, b1, Vw1, Vb1, Vw2,
                                            Vb2, W2, sW, vv, W1b_bf, W2_bf);
  main_kernel<<<B_TOT, 256, 0, stream>>>(agent_qs, b2, W3, b3, sW, vv,
                                         W1b_bf, W2_bf, out);
}

// Round 2
// 117.236 us; speedup vs baseline: 2.4311x; 2.4311x over previous
//
#include <hip/hip_runtime.h>

// SQDDPG mixer, MI355X. Round 7: R6 spilled (acc[4][4]+acc2[4][4] live ->
// 500 MB scratch traffic, 285 us). Restore R5's register discipline
// (sequential nh un-halves, acc[4][2]=32 regs, psum carry, (256,4)) while
// KEEPING R6's validated wins: prefix-major triangular layer-1 (MFMA
// 128->80/wave, A-builds 32->8/pass), h1 XOR swizzle (conflict-free
// scatter), merged prep+pack, remapped gather.
//
// Frozen validated facts (R2/R3): threefry partitionable, bits=o0^o1,
// counter (0, b*128+n); stable ranks; coalition slot j <- qs[inv_l[j]];
// output agent n reads prefix-row pos_l[n]; B-frag pack order: slot
// (t,u,L) elem j -> B[k=t*32+(L>>4)*8+j][n=u*16+(L&15)].
// Frozen validated facts (R6 pass): row map M-row = prefix*8+(s&7), pass
// p = s>>3; tile mt holds prefixes {2mt,2mt+1}; K-slice t contributes iff
// t<=mt; diagonal mask on = (q>>1)<=(l15>>3); h1 swizzle: unit index
// u = ub + ((q*4+r)^xr), reader lane Lsw = L ^ ((L>>3)&3); gather
// marg_l[(s>>3)*64 + pos*8 + (s&7)].

#define A_N   8
#define NA_N  16
#define S_N   16
#define SD    256
#define EMB   256
#define B_TOT 1024

typedef __bf16 bf16x8 __attribute__((ext_vector_type(8)));
typedef float  f32x4  __attribute__((ext_vector_type(4)));

__device__ __forceinline__ f32x4 splat4(float v) {
  f32x4 x; x[0] = v; x[1] = v; x[2] = v; x[3] = v; return x;
}
__device__ __forceinline__ bf16x8 zero8() {
  bf16x8 z;
#pragma unroll
  for (int j = 0; j < 8; ++j) z[j] = (__bf16)0.0f;
  return z;
}

// ---------------------------------------------------------------------------
// JAX threefry2x32, key = (0, 42); partitionable draw: bits = o0 ^ o1.
// ---------------------------------------------------------------------------
__device__ __forceinline__ float jax_uniform(unsigned idx) {
  const unsigned ks0 = 0u, ks1 = 42u, ks2 = 0x1BD11BDAu ^ 42u;
  unsigned x0 = 0u + ks0;
  unsigned x1 = idx + ks1;
#define TF_RND(r) { x0 += x1; x1 = (x1 << (r)) | (x1 >> (32 - (r))); x1 ^= x0; }
  TF_RND(13) TF_RND(15) TF_RND(26) TF_RND(6)  x0 += ks1; x1 += ks2 + 1u;
  TF_RND(17) TF_RND(29) TF_RND(16) TF_RND(24) x0 += ks2; x1 += ks0 + 2u;
  TF_RND(13) TF_RND(15) TF_RND(26) TF_RND(6)  x0 += ks0; x1 += ks1 + 3u;
  TF_RND(17) TF_RND(29) TF_RND(16) TF_RND(24) x0 += ks1; x1 += ks2 + 4u;
  TF_RND(13) TF_RND(15) TF_RND(26) TF_RND(6)  x0 += ks2; x1 += ks0 + 5u;
#undef TF_RND
  const unsigned bits = x0 ^ x1;
  return __uint_as_float((bits >> 9) | 0x3F800000u) - 1.0f;
}

// ---------------------------------------------------------------------------
// Merged prep (blocks 0..511: sW + V-net, 2 b each) + pack (blocks 512..559:
// bf16 B-frag repack of W1-bottom and W2).
// ---------------------------------------------------------------------------
__global__ __launch_bounds__(256) void prep_pack_kernel(
    const float* __restrict__ states, const float* __restrict__ W1,
    const float* __restrict__ b1, const float* __restrict__ Vw1,
    const float* __restrict__ Vb1, const float* __restrict__ Vw2,
    const float* __restrict__ Vb2, const float* __restrict__ W2,
    float* __restrict__ sW, float* __restrict__ vout,
    __bf16* __restrict__ W1b_bf, __bf16* __restrict__ W2_bf) {
  __shared__ float st_l[2][SD];
  __shared__ float red_l[2][4];

  if (blockIdx.x >= 512) {  // ---- pack path ----
    const int ts = (blockIdx.x - 512) * 256 + threadIdx.x;  // 0..12287
    if (ts < 4096) {                                // W1 bottom: t=0..3
      const int t = ts >> 10, rem = ts & 1023, u = rem >> 6, Lp = rem & 63;
      const int qp = Lp >> 4, l15p = Lp & 15;
#pragma unroll
      for (int j = 0; j < 8; ++j) {
        const int k = t * 32 + qp * 8 + j, nn = u * 16 + l15p;
        W1b_bf[ts * 8 + j] = (__bf16)W1[(SD + k) * EMB + nn];
      }
    } else {                                        // W2: t=0..7
      const int ts2 = ts - 4096;
      const int t = ts2 >> 10, rem = ts2 & 1023, u = rem >> 6, Lp = rem & 63;
      const int qp = Lp >> 4, l15p = Lp & 15;
#pragma unroll
      for (int j = 0; j < 8; ++j) {
        const int k = t * 32 + qp * 8 + j, nn = u * 16 + l15p;
        W2_bf[ts2 * 8 + j] = (__bf16)W2[k * EMB + nn];
      }
    }
    return;
  }

  // ---- prep path ----
  const int b0 = blockIdx.x * 2;
  const int n = threadIdx.x;

#pragma unroll
  for (int i = 0; i < 2; ++i) st_l[i][n] = states[(b0 + i) * SD + n];
  __syncthreads();

  float aS[2], aV[2];
  const float b1n = b1[n], vb1n = Vb1[n];
#pragma unroll
  for (int i = 0; i < 2; ++i) { aS[i] = b1n; aV[i] = vb1n; }

#pragma unroll 8
  for (int k = 0; k < SD; ++k) {
    const float wv = W1[k * EMB + n];
    const float vw = Vw1[k * EMB + n];
#pragma unroll
    for (int i = 0; i < 2; ++i) {
      const float s = st_l[i][k];
      aS[i] = fmaf(s, wv, aS[i]);
      aV[i] = fmaf(s, vw, aV[i]);
    }
  }
#pragma unroll
  for (int i = 0; i < 2; ++i) sW[(b0 + i) * EMB + n] = aS[i];

  const float vw2 = Vw2[n];
#pragma unroll
  for (int i = 0; i < 2; ++i) {
    float c = fmaxf(aV[i], 0.f) * vw2;
#pragma unroll
    for (int off = 32; off; off >>= 1) c += __shfl_down(c, off);
    if ((n & 63) == 0) red_l[i][n >> 6] = c;
  }
  __syncthreads();
  if (n < 2)
    vout[b0 + n] = red_l[n][0] + red_l[n][1] + red_l[n][2] + red_l[n][3] + Vb2[0];
}

// ---------------------------------------------------------------------------
// Main: 1024 blocks (one per b), 256 threads = 4 waves. Two passes of M=64,
// prefix-major rows, triangular layer-1. Column work split in two sequential
// un-halves: acc[4][2] live (32 regs), psum[4][4] carries layer-3 partials.
// ---------------------------------------------------------------------------
__global__ __launch_bounds__(256, 4) void main_kernel(
    const float* __restrict__ agent_qs, const float* __restrict__ b2g,
    const float* __restrict__ W3, const float* __restrict__ b3,
    const float* __restrict__ sW, const float* __restrict__ vv,
    const __bf16* __restrict__ W1b_bf, const __bf16* __restrict__ W2_bf,
    float* __restrict__ out) {
  __shared__ bf16x8 h1_l[32 * 64];      // 32 KB: layer2 A-frags (swizzled)
  __shared__ __attribute__((aligned(16))) __bf16 qs_bf[A_N * NA_N];
  __shared__ float u_l[128];
  __shared__ int   inv_l[128];          // inv_l[s*8+a] = rank of agent a
  __shared__ int   pos_l[128];          // pos_l[s*8+r] = agent with rank r
  __shared__ float adv_part[4][64];
  __shared__ float marg_l[128];         // marg_l[p*64 + prefix*8 + (s&7)]

  const int b = blockIdx.x;
  const int n = threadIdx.x;
  const int w = n >> 6, L = n & 63, q = L >> 4, l15 = L & 15;
  const int s7 = l15 & 7;        // s low bits (A-frag / C-row role)
  const int sl = l15 >> 3;       // prefix low bit (A-frag side)
  const int jq = q >> 1;         // jcoal low bit
  const int na0 = (q & 1) * 8;   // action sub-block
  const int Lsw = L ^ ((L >> 3) & 3);  // swizzled layer-2 read lane

  if (n < 128) {
    qs_bf[n] = (__bf16)agent_qs[b * 128 + n];
    u_l[n] = jax_uniform((unsigned)(b * 128 + n));
  }
  __syncthreads();

  if (n < 128) {
    const int s = n >> 3, a = n & 7;
    const float u = u_l[n];
    int r = 0;
#pragma unroll
    for (int a2 = 0; a2 < A_N; ++a2) {
      const float u2 = u_l[s * 8 + a2];
      r += (u2 < u || (u2 == u && a2 < a)) ? 1 : 0;
    }
    inv_l[n] = r;
    pos_l[s * 8 + r] = a;
  }
  __syncthreads();

  // diagonal-tile mask: t==mt -> on iff jcoal<=prefix iff jq<=sl
  const bool diag_on = (jq <= sl);

#pragma unroll 1
  for (int p = 0; p < 2; ++p) {
    const int invbase = (p * 8 + s7) * 8;

    // ---- layer 1: triangular (64x128)@W1b(128x256); 2 un-halves ----
#pragma unroll 1
    for (int nh = 0; nh < 2; ++nh) {
      f32x4 acc[4][2];
#pragma unroll
      for (int i = 0; i < 2; ++i) {
        const float sv = sW[b * EMB + (w * 4 + nh * 2 + i) * 16 + l15];
#pragma unroll
        for (int mt = 0; mt < 4; ++mt) acc[mt][i] = splat4(sv);
      }
#pragma unroll
      for (int t = 0; t < 4; ++t) {
        const int ag = inv_l[invbase + 2 * t + jq];
        const bf16x8 afb = *(const bf16x8*)&qs_bf[ag * NA_N + na0];
        const bf16x8 afd = diag_on ? afb : zero8();
        bf16x8 bfr[2];
#pragma unroll
        for (int i = 0; i < 2; ++i)
          bfr[i] = *(const bf16x8*)
              &W1b_bf[((t * 16 + w * 4 + nh * 2 + i) * 64 + L) * 8];
#pragma unroll
        for (int mt = 0; mt < 4; ++mt) {
          if (mt < t) continue;  // compile-time folded: t>mt is exact zero
#pragma unroll
          for (int i = 0; i < 2; ++i)
            acc[mt][i] = __builtin_amdgcn_mfma_f32_16x16x32_bf16(
                (mt == t) ? afd : afb, bfr[i], acc[mt][i], 0, 0, 0);
        }
      }
      // relu -> bf16 swizzled scatter (conflict-free; R6-validated formula)
      __bf16* h1e = (__bf16*)h1_l;
#pragma unroll
      for (int i = 0; i < 2; ++i) {
        const int X = w * 4 + nh * 2 + i;
        const int hi = (X & 1) * 2 + sl;
        const int xr = (q >> 1) | ((hi & 1) << 1);
#pragma unroll
        for (int mt = 0; mt < 4; ++mt) {
          const int ub = ((X >> 1) * 4 + mt) * 64 + (hi << 4);
#pragma unroll
          for (int r = 0; r < 4; ++r) {
            const float v = fmaxf(acc[mt][i][r], 0.f);
            const int u = ub + ((q * 4 + r) ^ xr);
            h1e[u * 8 + s7] = (__bf16)v;
          }
        }
      }
    }
    __syncthreads();

    // ---- layer 2 + layer 3 partials: 2 un-halves, psum across halves ----
    float psum[4][4];
#pragma unroll
    for (int mt = 0; mt < 4; ++mt)
#pragma unroll
      for (int r = 0; r < 4; ++r) psum[mt][r] = 0.f;

#pragma unroll 1
    for (int nh = 0; nh < 2; ++nh) {
      f32x4 acc[4][2];
#pragma unroll
      for (int i = 0; i < 2; ++i) {
        const float bv = b2g[(w * 4 + nh * 2 + i) * 16 + l15];
#pragma unroll
        for (int mt = 0; mt < 4; ++mt) acc[mt][i] = splat4(bv);
      }
#pragma unroll 2
      for (int t = 0; t < 8; ++t) {
        bf16x8 bfr[2];
#pragma unroll
        for (int i = 0; i < 2; ++i)
          bfr[i] = *(const bf16x8*)
              &W2_bf[((t * 16 + w * 4 + nh * 2 + i) * 64 + L) * 8];
#pragma unroll
        for (int mt = 0; mt < 4; ++mt) {
          const bf16x8 af = h1_l[(t * 4 + mt) * 64 + Lsw];
#pragma unroll
          for (int i = 0; i < 2; ++i)
            acc[mt][i] = __builtin_amdgcn_mfma_f32_16x16x32_bf16(
                af, bfr[i], acc[mt][i], 0, 0, 0);
        }
      }
#pragma unroll
      for (int i = 0; i < 2; ++i) {
        const float w3v = W3[(w * 4 + nh * 2 + i) * 16 + l15];
#pragma unroll
        for (int mt = 0; mt < 4; ++mt)
#pragma unroll
          for (int r = 0; r < 4; ++r)
            psum[mt][r] = fmaf(fmaxf(acc[mt][i][r], 0.f), w3v, psum[mt][r]);
      }
    }

    // ---- reduce 16 cols per quad, combine waves via LDS ----
#pragma unroll
    for (int mt = 0; mt < 4; ++mt) {
#pragma unroll
      for (int r = 0; r < 4; ++r) {
        float sum = psum[mt][r];
#pragma unroll
        for (int off = 1; off < 16; off <<= 1) sum += __shfl_xor(sum, off);
        if (l15 == 0) adv_part[w][mt * 16 + q * 4 + r] = sum;
      }
    }
    __syncthreads();
    if (n < 64)
      marg_l[p * 64 + n] = adv_part[0][n] + adv_part[1][n] +
                           adv_part[2][n] + adv_part[3][n];
    __syncthreads();
  }

  // ---- gather: agent a at sample s -> row prefix*8 + (s&7), p = s>>3 ----
  if (n < A_N) {
    float sh = 0.f;
#pragma unroll
    for (int s = 0; s < S_N; ++s) {
      const int pr = pos_l[s * 8 + n];
      sh += marg_l[((s >> 3) << 6) + pr * 8 + (s & 7)];
    }
    out[b * A_N + n] = sh * (1.f / 16.f) + b3[0] + vv[b];
  }
}

// ---------------------------------------------------------------------------
extern "C" void kernel_launch(void* const* d_in, const int* in_sizes, int n_in,
                              void* d_out, int out_size, void* d_ws,
                              size_t ws_size, hipStream_t stream) {
  const float* states   = (const float*)d_in[0];
  const float* agent_qs = (const float*)d_in[1];
  const float* W1       = (const float*)d_in[2];
  const float* b1       = (const float*)d_in[3];
  const float* W2       = (const float*)d_in[4];
  const float* b2       = (const float*)d_in[5];
  const float* W3       = (const float*)d_in[6];
  const float* b3       = (const float*)d_in[7];
  const float* Vw1      = (const float*)d_in[8];
  const float* Vb1      = (const float*)d_in[9];
  const float* Vw2      = (const float*)d_in[10];
  const float* Vb2      = (const float*)d_in[11];
  float* out = (float*)d_out;

  char* ws = (char*)d_ws;
  float*  sW     = (float*)(ws);                     // 1 MB
  float*  vv     = (float*)(ws + 1048576);           // 4 KB
  __bf16* W1b_bf = (__bf16*)(ws + 1052672);          // 64 KB
  __bf16* W2_bf  = (__bf16*)(ws + 1118208);          // 128 KB

  prep_pack_kernel<<<560, 256, 0, stream>>>(states, W1, b1, Vw1, Vb1, Vw2,
                                            Vb2, W2, sW, vv, W1b_bf, W2_bf);
  main_kernel<<<B_TOT, 256, 0, stream>>>(agent_qs, b2, W3, b3, sW, vv,
                                         W1b_bf, W2_bf, out);
}